// Round 3
// baseline (699.950 us; speedup 1.0000x reference)
//
#include <hip/hip_runtime.h>
#include <hip/hip_bf16.h>
#include <math.h>

// Problem constants
#define Bq 64
#define Tt 2048
#define TQn 2
#define HIDn 1024
#define ENCn 512
#define Un 256
#define FILTn 32
#define KKn 31

// Main-pass tiling
#define TTILE 64
#define NCHUNK (Tt / TTILE)     // 32

typedef short short8 __attribute__((ext_vector_type(8)));
typedef float f32x4  __attribute__((ext_vector_type(4)));
typedef unsigned short ushort_t;
typedef unsigned int   uint_t;

union S8 { short8 v; uint_t u[4]; };

__device__ __forceinline__ ushort_t f2b(float f) {          // RNE scalar (prep only)
    union { float f; uint_t u; } x; x.f = f;
    uint_t r = x.u + 0x7fffu + ((x.u >> 16) & 1u);
    return (ushort_t)(r >> 16);
}
__device__ __forceinline__ uint_t cvt_pk(float lo, float hi) {  // HW v_cvt_pk_bf16_f32
    union { __hip_bfloat162 h; uint_t u; } x;
    x.h = __float22bfloat162_rn(make_float2(lo, hi));
    return x.u;
}
__device__ __forceinline__ float tanh_fast(float x) {
    const float e = __expf(2.0f * x);
    return 1.0f - 2.0f * __builtin_amdgcn_rcpf(e + 1.0f);
}

// ---------------- prep1: WqWe, WmWeT, WlWe->CWT, cvec (one wide dispatch) ----------------
__global__ void k_prep1(const float* __restrict__ Wq, const float* __restrict__ We,
                        const float* __restrict__ Wm, const float* __restrict__ Wl,
                        const float* __restrict__ conv_w, const float* __restrict__ bq,
                        const float* __restrict__ bm, const float* __restrict__ bl,
                        const float* __restrict__ conv_b,
                        float* __restrict__ WqWe, ushort_t* __restrict__ WmWeT,
                        ushort_t* __restrict__ CWT, float* __restrict__ cvec)
{
    const int blk = blockIdx.x;
    const int v = threadIdx.x;
    if (blk < 1024) {                      // WqWe[h,v] = sum_u Wq[h,u] We[u,v]
        const int h = blk;
        float a0 = 0.f, a1 = 0.f, a2 = 0.f, a3 = 0.f;
        #pragma unroll 4
        for (int u = 0; u < Un; u += 4) {
            a0 += Wq[h * Un + u + 0] * We[(u + 0) * Un + v];
            a1 += Wq[h * Un + u + 1] * We[(u + 1) * Un + v];
            a2 += Wq[h * Un + u + 2] * We[(u + 2) * Un + v];
            a3 += Wq[h * Un + u + 3] * We[(u + 3) * Un + v];
        }
        WqWe[(size_t)h * Un + v] = (a0 + a1) + (a2 + a3);
    } else if (blk < 1536) {               // WmWeT[v,e] = bf16(sum_u Wm[e,u] We[u,v])
        const int e = blk - 1024;
        float a0 = 0.f, a1 = 0.f, a2 = 0.f, a3 = 0.f;
        #pragma unroll 4
        for (int u = 0; u < Un; u += 4) {
            a0 += Wm[(size_t)e * Un + u + 0] * We[(u + 0) * Un + v];
            a1 += Wm[(size_t)e * Un + u + 1] * We[(u + 1) * Un + v];
            a2 += Wm[(size_t)e * Un + u + 2] * We[(u + 2) * Un + v];
            a3 += Wm[(size_t)e * Un + u + 3] * We[(u + 3) * Un + v];
        }
        WmWeT[(size_t)v * ENCn + e] = f2b((a0 + a1) + (a2 + a3));
    } else if (blk < 1540) {               // CWT[v,k] for a 64-wide v chunk
        const int vc = (blk - 1536) * 64;
        __shared__ float wlwe[FILTn * 64];
        for (int i = threadIdx.x; i < FILTn * 64; i += 256) {
            const int f = i >> 6, vv = i & 63;
            float a = 0.f;
            #pragma unroll 8
            for (int u = 0; u < Un; ++u) a += Wl[f * Un + u] * We[u * Un + vc + vv];
            wlwe[f * 64 + vv] = a;
        }
        __syncthreads();
        for (int i = threadIdx.x; i < 64 * 32; i += 256) {
            const int vv = i >> 5, k = i & 31;
            float a = 0.f;
            if (k < KKn) {
                #pragma unroll
                for (int f = 0; f < FILTn; ++f) a += conv_w[f * KKn + k] * wlwe[f * 64 + vv];
            }
            CWT[(size_t)(vc + vv) * 32 + k] = f2b(a);
        }
    } else {                               // cvec[u] = bq+bm+bl+conv_b@Wl
        const int u = v;
        float a = bq[u] + bm[u] + bl[u];
        #pragma unroll
        for (int f = 0; f < FILTn; ++f) a += conv_b[f] * Wl[f * Un + u];
        cvec[u] = a;
    }
}

// ---------------- prep2: zconst[b,v] = q1@WqWe + cvec@We + be ----------------
__global__ void k_prep2(const float* __restrict__ query, const float* __restrict__ WqWe,
                        const float* __restrict__ cvec, const float* __restrict__ We,
                        const float* __restrict__ be, float* __restrict__ zconst)
{
    const int b = blockIdx.x, h0 = blockIdx.y * 256, v = threadIdx.x;
    const float* q = query + ((size_t)b * TQn + 1) * HIDn;
    float a0 = 0.f, a1 = 0.f, a2 = 0.f, a3 = 0.f;
    #pragma unroll 4
    for (int h = 0; h < 256; h += 4) {
        a0 += q[h0 + h + 0] * WqWe[(size_t)(h0 + h + 0) * Un + v];
        a1 += q[h0 + h + 1] * WqWe[(size_t)(h0 + h + 1) * Un + v];
        a2 += q[h0 + h + 2] * WqWe[(size_t)(h0 + h + 2) * Un + v];
        a3 += q[h0 + h + 3] * WqWe[(size_t)(h0 + h + 3) * Un + v];
    }
    float acc = (a0 + a1) + (a2 + a3);
    if (blockIdx.y == 0) {
        acc += be[v];
        float c0 = 0.f, c1 = 0.f;
        #pragma unroll 4
        for (int u = 0; u < Un; u += 2) {
            c0 += cvec[u]     * We[u * Un + v];
            c1 += cvec[u + 1] * We[(u + 1) * Un + v];
        }
        acc += c0 + c1;
    }
    atomicAdd(&zconst[b * Un + v], acc);
}

// ---------------- main fused MFMA pass (no LDS staging) ----------------
// Block: (b, 64-row t-chunk), 256 thr = 4 waves; wave w owns v-cols w*64..w*64+63.
// A-frags read directly from global fp32 -> cvt_pk -> bf16; B from L2 (WmWeT).
__global__ __launch_bounds__(256, 2) void attn_main(
    const float* __restrict__ memory, const float* __restrict__ state,
    const ushort_t* __restrict__ WmWeT, const ushort_t* __restrict__ CWT,
    const float* __restrict__ zconst, const float* __restrict__ v_a,
    float* __restrict__ zA, float* __restrict__ zS,
    float* __restrict__ zSsum, float* __restrict__ zStsum)
{
    const int blk = blockIdx.x;
    const int b  = blk >> 5;
    const int c  = blk & (NCHUNK - 1);
    const int t0 = c * TTILE;
    const int tid = threadIdx.x;

    __shared__ __align__(16) float sw_raw[100];
    __shared__ __align__(16) float ep_s[4][TTILE];
    __shared__ __align__(16) float s_s[TTILE];
    float* sw = sw_raw + 1;   // sw[i] = state[t0-15+i]; sw[15+4k] 16B-aligned

    for (int i = tid; i < TTILE + 31; i += 256) {
        const int t = t0 - 15 + i;
        sw[i] = (t >= 0 && t < Tt) ? state[b * Tt + t] : 0.0f;
    }

    const int lane = tid & 63;
    const int w    = tid >> 6;
    const int lm   = lane & 15;
    const int lq   = lane >> 4;
    const int ncol0 = w * 64 + lm;

    // A pointers: row (16m+lm), col lq*8 + s*32 (fp32, 2 float4 per frag)
    const float* abase = memory + ((size_t)b * Tt + t0) * ENCn + lq * 8;
    const float* ap0 = abase + (size_t)(lm +  0) * ENCn;
    const float* ap1 = abase + (size_t)(lm + 16) * ENCn;
    const float* ap2 = abase + (size_t)(lm + 32) * ENCn;
    const float* ap3 = abase + (size_t)(lm + 48) * ENCn;

    const ushort_t* bp0 = WmWeT + (size_t)(ncol0 +  0) * ENCn + lq * 8;
    const ushort_t* bp1 = WmWeT + (size_t)(ncol0 + 16) * ENCn + lq * 8;
    const ushort_t* bp2 = WmWeT + (size_t)(ncol0 + 32) * ENCn + lq * 8;
    const ushort_t* bp3 = WmWeT + (size_t)(ncol0 + 48) * ENCn + lq * 8;

    f32x4 acc[4][4] = {};

    // prefetch step 0
    float4 an[4][2];
    an[0][0] = *(const float4*)(ap0); an[0][1] = *(const float4*)(ap0 + 4);
    an[1][0] = *(const float4*)(ap1); an[1][1] = *(const float4*)(ap1 + 4);
    an[2][0] = *(const float4*)(ap2); an[2][1] = *(const float4*)(ap2 + 4);
    an[3][0] = *(const float4*)(ap3); an[3][1] = *(const float4*)(ap3 + 4);
    short8 bn0 = *(const short8*)bp0;
    short8 bn1 = *(const short8*)bp1;
    short8 bn2 = *(const short8*)bp2;
    short8 bn3 = *(const short8*)bp3;

    #pragma unroll 4
    for (int s = 0; s < 16; ++s) {
        // convert current A, copy current B
        S8 a[4];
        #pragma unroll
        for (int m = 0; m < 4; ++m) {
            a[m].u[0] = cvt_pk(an[m][0].x, an[m][0].y);
            a[m].u[1] = cvt_pk(an[m][0].z, an[m][0].w);
            a[m].u[2] = cvt_pk(an[m][1].x, an[m][1].y);
            a[m].u[3] = cvt_pk(an[m][1].z, an[m][1].w);
        }
        const short8 b0 = bn0, b1 = bn1, b2 = bn2, b3 = bn3;
        // prefetch next step (s=15 redundantly reloads step 0; L1-hot, branch-free)
        const int sn = ((s + 1) & 15) * 32;
        an[0][0] = *(const float4*)(ap0 + sn); an[0][1] = *(const float4*)(ap0 + sn + 4);
        an[1][0] = *(const float4*)(ap1 + sn); an[1][1] = *(const float4*)(ap1 + sn + 4);
        an[2][0] = *(const float4*)(ap2 + sn); an[2][1] = *(const float4*)(ap2 + sn + 4);
        an[3][0] = *(const float4*)(ap3 + sn); an[3][1] = *(const float4*)(ap3 + sn + 4);
        bn0 = *(const short8*)(bp0 + sn);
        bn1 = *(const short8*)(bp1 + sn);
        bn2 = *(const short8*)(bp2 + sn);
        bn3 = *(const short8*)(bp3 + sn);

        #pragma unroll
        for (int m = 0; m < 4; ++m) {
            acc[m][0] = __builtin_amdgcn_mfma_f32_16x16x32_bf16(a[m].v, b0, acc[m][0], 0, 0, 0);
            acc[m][1] = __builtin_amdgcn_mfma_f32_16x16x32_bf16(a[m].v, b1, acc[m][1], 0, 0, 0);
            acc[m][2] = __builtin_amdgcn_mfma_f32_16x16x32_bf16(a[m].v, b2, acc[m][2], 0, 0, 0);
            acc[m][3] = __builtin_amdgcn_mfma_f32_16x16x32_bf16(a[m].v, b3, acc[m][3], 0, 0, 0);
        }
    }

    __syncthreads();   // sw ready (also all waves past state staging)

    // conv as one extra K=32 MFMA step: A[t][k] = sw[t + k], B = CWT
    {
        S8 ca[4];
        #pragma unroll
        for (int m = 0; m < 4; ++m) {
            const int base = 16 * m + lm + lq * 8;
            #pragma unroll
            for (int j = 0; j < 4; ++j)
                ca[m].u[j] = cvt_pk(sw[base + 2 * j], sw[base + 2 * j + 1]);
        }
        const ushort_t* cp = CWT + (size_t)ncol0 * 32 + lq * 8;
        const short8 cb0 = *(const short8*)(cp);
        const short8 cb1 = *(const short8*)(cp + 16 * 32);
        const short8 cb2 = *(const short8*)(cp + 32 * 32);
        const short8 cb3 = *(const short8*)(cp + 48 * 32);
        #pragma unroll
        for (int m = 0; m < 4; ++m) {
            acc[m][0] = __builtin_amdgcn_mfma_f32_16x16x32_bf16(ca[m].v, cb0, acc[m][0], 0, 0, 0);
            acc[m][1] = __builtin_amdgcn_mfma_f32_16x16x32_bf16(ca[m].v, cb1, acc[m][1], 0, 0, 0);
            acc[m][2] = __builtin_amdgcn_mfma_f32_16x16x32_bf16(ca[m].v, cb2, acc[m][2], 0, 0, 0);
            acc[m][3] = __builtin_amdgcn_mfma_f32_16x16x32_bf16(ca[m].v, cb3, acc[m][3], 0, 0, 0);
        }
    }

    // epilogue: zconst + tanh + v_a dot; reduce over the 16 n-lanes
    float zc[4], va[4];
    #pragma unroll
    for (int nbi = 0; nbi < 4; ++nbi) {
        const int col = ncol0 + nbi * 16;
        zc[nbi] = zconst[b * Un + col];
        va[nbi] = v_a[col];
    }
    #pragma unroll
    for (int mi = 0; mi < 4; ++mi) {
        #pragma unroll
        for (int r = 0; r < 4; ++r) {
            float ep = 0.f;
            #pragma unroll
            for (int nbi = 0; nbi < 4; ++nbi)
                ep += tanh_fast(acc[mi][nbi][r] + zc[nbi]) * va[nbi];
            ep += __shfl_xor(ep, 1, 64);
            ep += __shfl_xor(ep, 2, 64);
            ep += __shfl_xor(ep, 4, 64);
            ep += __shfl_xor(ep, 8, 64);
            if (lm == 0) ep_s[w][16 * mi + 4 * lq + r] = ep;   // C/D: row = quad*4+reg
        }
    }
    __syncthreads();

    if (tid < 64) {
        const float energy = ep_s[0][tid] + ep_s[1][tid] + ep_s[2][tid] + ep_s[3][tid];
        const float s = __builtin_amdgcn_rcpf(1.0f + __expf(-energy));
        s_s[tid] = s;
        float st = sw[15 + tid];
        float ssum = s, stsum = st;
        #pragma unroll
        for (int off = 32; off >= 1; off >>= 1) {
            ssum  += __shfl_xor(ssum,  off, 64);
            stsum += __shfl_xor(stsum, off, 64);
        }
        if (tid == 0) {
            atomicAdd(&zSsum[b], ssum);
            atomicAdd(&zStsum[b], stsum);
        }
    }
    __syncthreads();

    // A/S weighted accumulation, fp32, tile re-read from L2 (coalesced float2/lane)
    const int e0 = tid << 1;
    const float* mcol = memory + ((size_t)b * Tt + t0) * ENCn + e0;
    float aA0 = 0.f, aA1 = 0.f, aS0 = 0.f, aS1 = 0.f;
    #pragma unroll 2
    for (int r4 = 0; r4 < TTILE / 4; ++r4) {
        const float4 st4 = *(const float4*)&sw[15 + 4 * r4];
        const float4 sv4 = *(const float4*)&s_s[4 * r4];
        const float st[4] = {st4.x, st4.y, st4.z, st4.w};
        const float sv[4] = {sv4.x, sv4.y, sv4.z, sv4.w};
        #pragma unroll
        for (int j = 0; j < 4; ++j) {
            const float2 m = *(const float2*)(mcol + (size_t)(4 * r4 + j) * ENCn);
            aA0 += st[j] * m.x; aA1 += st[j] * m.y;
            aS0 += sv[j] * m.x; aS1 += sv[j] * m.y;
        }
    }
    atomicAdd(&zA[b * ENCn + e0],     aA0);
    atomicAdd(&zA[b * ENCn + e0 + 1], aA1);
    atomicAdd(&zS[b * ENCn + e0],     aS0);
    atomicAdd(&zS[b * ENCn + e0 + 1], aS1);
}

// ---------------- finalize ----------------
__global__ void k_final(const float* __restrict__ zA, const float* __restrict__ zS,
                        const float* __restrict__ zSsum, const float* __restrict__ zStsum,
                        const float* __restrict__ Wm, const float* __restrict__ bm,
                        float* __restrict__ out)
{
    const int b = blockIdx.x, e0 = blockIdx.y * 128, u = threadIdx.x;
    const float inv = 1.0f / zSsum[b];
    float a0 = 0.f, a1 = 0.f;
    #pragma unroll 4
    for (int e = e0; e < e0 + 128; e += 2) {
        const float c0 = zA[b * ENCn + e]     + zS[b * ENCn + e]     * inv;
        const float c1 = zA[b * ENCn + e + 1] + zS[b * ENCn + e + 1] * inv;
        a0 += c0 * Wm[(size_t)e * Un + u];
        a1 += c1 * Wm[(size_t)(e + 1) * Un + u];
    }
    float acc = a0 + a1;
    if (blockIdx.y == 0) acc += bm[u] * (zStsum[b] + 1.0f);
    atomicAdd(&out[b * Un + u], acc);
}

// ---------------- launch ----------------
extern "C" void kernel_launch(void* const* d_in, const int* in_sizes, int n_in,
                              void* d_out, int out_size, void* d_ws, size_t ws_size,
                              hipStream_t stream)
{
    const float* query  = (const float*)d_in[0];
    const float* state  = (const float*)d_in[1];
    const float* memory = (const float*)d_in[2];
    const float* Wq     = (const float*)d_in[3];
    const float* bq     = (const float*)d_in[4];
    const float* Wm     = (const float*)d_in[5];
    const float* bm     = (const float*)d_in[6];
    const float* Wl     = (const float*)d_in[7];
    const float* bl     = (const float*)d_in[8];
    const float* conv_w = (const float*)d_in[9];
    const float* conv_b = (const float*)d_in[10];
    const float* We     = (const float*)d_in[11];
    const float* be     = (const float*)d_in[12];
    const float* v_a    = (const float*)d_in[13];
    float* out = (float*)d_out;

    // workspace layout (float offsets)
    float* ws      = (float*)d_ws;
    float* zA      = ws;                   // 32768
    float* zS      = ws + 32768;           // 32768
    float* zSsum   = ws + 65536;           // 64
    float* zStsum  = ws + 65600;           // 64
    float* zconst  = ws + 65664;           // 16384   (zero region ends at 82048)
    float* WqWe    = ws + 82048;           // 262144
    float* cvec    = ws + 344192;          // 256
    ushort_t* WmWeT = (ushort_t*)(ws + 344448);  // 131072 ushorts
    ushort_t* CWT   = (ushort_t*)(ws + 409984);  // 8192 ushorts -> ends 414080 floats (~1.66 MB)

    hipMemsetAsync(ws, 0, 82048 * sizeof(float), stream);
    hipMemsetAsync(out, 0, (size_t)Bq * Un * sizeof(float), stream);

    hipLaunchKernelGGL(k_prep1, dim3(1541), dim3(Un), 0, stream,
                       Wq, We, Wm, Wl, conv_w, bq, bm, bl, conv_b,
                       WqWe, WmWeT, CWT, cvec);
    hipLaunchKernelGGL(k_prep2, dim3(Bq, 4), dim3(Un), 0, stream,
                       query, WqWe, cvec, We, be, zconst);
    hipLaunchKernelGGL(attn_main, dim3(Bq * NCHUNK), dim3(256), 0, stream,
                       memory, state, WmWeT, CWT, zconst, v_a, zA, zS, zSsum, zStsum);
    hipLaunchKernelGGL(k_final, dim3(Bq, 4), dim3(Un), 0, stream,
                       zA, zS, zSsum, zStsum, Wm, bm, out);
}

// Round 4
// 559.851 us; speedup vs baseline: 1.2502x; 1.2502x over previous
//
#include <hip/hip_runtime.h>
#include <hip/hip_bf16.h>
#include <math.h>

// Problem constants
#define Bq 64
#define Tt 2048
#define TQn 2
#define HIDn 1024
#define ENCn 512
#define Un 256
#define FILTn 32
#define KKn 31

// Main-pass tiling
#define TTILE 32
#define NCHUNK (Tt / TTILE)     // 64
#define LDK 520                 // padded LDS row (bf16): 512+8, 16B-aligned rows

typedef short short8 __attribute__((ext_vector_type(8)));
typedef float f32x4  __attribute__((ext_vector_type(4)));
typedef unsigned short ushort_t;
typedef unsigned int   uint_t;

union S8 { short8 v; uint_t u[4]; };

__device__ __forceinline__ ushort_t f2b(float f) {          // RNE scalar (prep only)
    union { float f; uint_t u; } x; x.f = f;
    uint_t r = x.u + 0x7fffu + ((x.u >> 16) & 1u);
    return (ushort_t)(r >> 16);
}
__device__ __forceinline__ uint_t cvt_pk(float lo, float hi) {  // HW v_cvt_pk_bf16_f32
    union { __hip_bfloat162 h; uint_t u; } x;
    x.h = __float22bfloat162_rn(make_float2(lo, hi));
    return x.u;
}
__device__ __forceinline__ float b2f(uint_t u16) {
    union { uint_t i; float f; } x; x.i = u16 << 16;
    return x.f;
}
__device__ __forceinline__ float tanh_fast(float x) {
    const float e = __expf(2.0f * x);
    return 1.0f - 2.0f * __builtin_amdgcn_rcpf(e + 1.0f);
}

// ---------------- prep1: WmWeT, CWT, cvec (one dispatch, 517 blocks) ----------------
__global__ void k_prep1(const float* __restrict__ We, const float* __restrict__ Wm,
                        const float* __restrict__ Wl, const float* __restrict__ conv_w,
                        const float* __restrict__ bq, const float* __restrict__ bm,
                        const float* __restrict__ bl, const float* __restrict__ conv_b,
                        ushort_t* __restrict__ WmWeT, ushort_t* __restrict__ CWT,
                        float* __restrict__ cvec)
{
    const int blk = blockIdx.x;
    const int v = threadIdx.x;
    if (blk < 512) {               // WmWeT[v,e] = bf16(sum_u Wm[e,u] We[u,v])
        const int e = blk;
        float a0 = 0.f, a1 = 0.f, a2 = 0.f, a3 = 0.f;
        #pragma unroll 4
        for (int u = 0; u < Un; u += 4) {
            a0 += Wm[(size_t)e * Un + u + 0] * We[(u + 0) * Un + v];
            a1 += Wm[(size_t)e * Un + u + 1] * We[(u + 1) * Un + v];
            a2 += Wm[(size_t)e * Un + u + 2] * We[(u + 2) * Un + v];
            a3 += Wm[(size_t)e * Un + u + 3] * We[(u + 3) * Un + v];
        }
        WmWeT[(size_t)v * ENCn + e] = f2b((a0 + a1) + (a2 + a3));
    } else if (blk < 516) {        // CWT[v,k] for a 64-wide v chunk
        const int vc = (blk - 512) * 64;
        __shared__ float wlwe[FILTn * 64];
        for (int i = threadIdx.x; i < FILTn * 64; i += 256) {
            const int f = i >> 6, vv = i & 63;
            float a = 0.f;
            #pragma unroll 8
            for (int u = 0; u < Un; ++u) a += Wl[f * Un + u] * We[u * Un + vc + vv];
            wlwe[f * 64 + vv] = a;
        }
        __syncthreads();
        for (int i = threadIdx.x; i < 64 * 32; i += 256) {
            const int vv = i >> 5, k = i & 31;
            float a = 0.f;
            if (k < KKn) {
                #pragma unroll
                for (int f = 0; f < FILTn; ++f) a += conv_w[f * KKn + k] * wlwe[f * 64 + vv];
            }
            CWT[(size_t)(vc + vv) * 32 + k] = f2b(a);
        }
    } else {                       // cvec[u] = bq+bm+bl+conv_b@Wl
        const int u = v;
        float a = bq[u] + bm[u] + bl[u];
        #pragma unroll
        for (int f = 0; f < FILTn; ++f) a += conv_b[f] * Wl[f * Un + u];
        cvec[u] = a;
    }
}

// ---------------- k_g: g[b,u] = q1@Wq (+cvec at y==0). grid (64,8), atomic ----------------
__global__ void k_g(const float* __restrict__ query, const float* __restrict__ Wq,
                    const float* __restrict__ cvec, float* __restrict__ g)
{
    const int b = blockIdx.x, hs = blockIdx.y * 128, u = threadIdx.x;
    const float* q = query + ((size_t)b * TQn + 1) * HIDn + hs;
    float a0 = 0.f, a1 = 0.f, a2 = 0.f, a3 = 0.f;
    #pragma unroll 4
    for (int h = 0; h < 128; h += 4) {
        a0 += q[h + 0] * Wq[(size_t)(hs + h + 0) * Un + u];
        a1 += q[h + 1] * Wq[(size_t)(hs + h + 1) * Un + u];
        a2 += q[h + 2] * Wq[(size_t)(hs + h + 2) * Un + u];
        a3 += q[h + 3] * Wq[(size_t)(hs + h + 3) * Un + u];
    }
    float acc = (a0 + a1) + (a2 + a3);
    if (blockIdx.y == 0) acc += cvec[u];
    atomicAdd(&g[b * Un + u], acc);
}

// ---------------- k_zconst: zconst[b,v] = g@We (+be at y==0). grid (64,4), atomic ----------------
__global__ void k_zconst(const float* __restrict__ g, const float* __restrict__ We,
                         const float* __restrict__ be, float* __restrict__ zconst)
{
    const int b = blockIdx.x, us = blockIdx.y * 64, v = threadIdx.x;
    float a0 = 0.f, a1 = 0.f;
    #pragma unroll 4
    for (int u = us; u < us + 64; u += 2) {
        a0 += g[b * Un + u]     * We[(size_t)u * Un + v];
        a1 += g[b * Un + u + 1] * We[(size_t)(u + 1) * Un + v];
    }
    float acc = a0 + a1;
    if (blockIdx.y == 0) acc += be[v];
    atomicAdd(&zconst[b * Un + v], acc);
}

// ---------------- main fused MFMA pass (LDS-staged tile + 2-deep B prefetch) ----------------
// Block: (b, 32-row t-chunk), 256 thr = 4 waves; wave w owns v-cols w*64..w*64+63.
__global__ __launch_bounds__(256, 4) void attn_main(
    const float* __restrict__ memory, const float* __restrict__ state,
    const ushort_t* __restrict__ WmWeT, const ushort_t* __restrict__ CWT,
    const float* __restrict__ zconst, const float* __restrict__ v_a,
    float* __restrict__ zA, float* __restrict__ zS,
    float* __restrict__ zSsum, float* __restrict__ zStsum)
{
    const int blk = blockIdx.x;
    const int b  = blk >> 6;            // / NCHUNK
    const int c  = blk & (NCHUNK - 1);
    const int t0 = c * TTILE;
    const int tid = threadIdx.x;

    __shared__ __align__(16) ushort_t mem_s[TTILE * LDK];   // 33280 B
    __shared__ __align__(16) float sw_raw[80];
    __shared__ __align__(16) float ep_s[4][TTILE];
    __shared__ __align__(16) float s_s[TTILE];
    float* sw = sw_raw + 1;   // sw[i] = state[t0-15+i]

    // state window [t0-15, t0+47], zero-padded at sequence ends
    for (int i = tid; i < TTILE + 31; i += 256) {
        const int t = t0 - 15 + i;
        sw[i] = (t >= 0 && t < Tt) ? state[b * Tt + t] : 0.0f;
    }

    const int lane = tid & 63;
    const int w    = tid >> 6;
    const int lm   = lane & 15;
    const int lq   = lane >> 4;
    const int ncol0 = w * 64 + lm;

    const ushort_t* bp0 = WmWeT + (size_t)(ncol0 +  0) * ENCn + lq * 8;
    const ushort_t* bp1 = WmWeT + (size_t)(ncol0 + 16) * ENCn + lq * 8;
    const ushort_t* bp2 = WmWeT + (size_t)(ncol0 + 32) * ENCn + lq * 8;
    const ushort_t* bp3 = WmWeT + (size_t)(ncol0 + 48) * ENCn + lq * 8;

    // 2-deep B prefetch: steps 0 and 1 issued before the staging barrier
    short8 bbuf[2][4];
    bbuf[0][0] = *(const short8*)(bp0);      bbuf[0][1] = *(const short8*)(bp1);
    bbuf[0][2] = *(const short8*)(bp2);      bbuf[0][3] = *(const short8*)(bp3);
    bbuf[1][0] = *(const short8*)(bp0 + 32); bbuf[1][1] = *(const short8*)(bp1 + 32);
    bbuf[1][2] = *(const short8*)(bp2 + 32); bbuf[1][3] = *(const short8*)(bp3 + 32);

    // stage 32x512 fp32 -> bf16 LDS tile
    const float4* memv4 = (const float4*)(memory + ((size_t)b * Tt + t0) * ENCn);
    #pragma unroll
    for (int i = 0; i < 8; ++i) {
        const int idx = i * 256 + tid;          // 8-float chunk id, 0..2047
        const int row = idx >> 6;               // 64 chunks per row
        const int cw8 = (idx & 63) << 3;
        const float4 m0 = memv4[2 * idx];
        const float4 m1 = memv4[2 * idx + 1];
        S8 v;
        v.u[0] = cvt_pk(m0.x, m0.y); v.u[1] = cvt_pk(m0.z, m0.w);
        v.u[2] = cvt_pk(m1.x, m1.y); v.u[3] = cvt_pk(m1.z, m1.w);
        *(short8*)&mem_s[row * LDK + cw8] = v.v;
    }

    f32x4 acc[2][4] = {};

    __syncthreads();

    const ushort_t* arow0 = &mem_s[(lm) * LDK + lq * 8];
    const ushort_t* arow1 = &mem_s[(16 + lm) * LDK + lq * 8];

    // A pipeline: load step 0
    short8 a0c = *(const short8*)(arow0);
    short8 a1c = *(const short8*)(arow1);

    #pragma unroll
    for (int s = 0; s < 16; ++s) {
        // A for step s+1 (LDS; s=15 redundant reload of step 0)
        const int sa = ((s + 1) & 15) * 32;
        const short8 a0n = *(const short8*)(arow0 + sa);
        const short8 a1n = *(const short8*)(arow1 + sa);
        // MFMA with current A and bbuf[s&1]
        acc[0][0] = __builtin_amdgcn_mfma_f32_16x16x32_bf16(a0c, bbuf[s & 1][0], acc[0][0], 0, 0, 0);
        acc[0][1] = __builtin_amdgcn_mfma_f32_16x16x32_bf16(a0c, bbuf[s & 1][1], acc[0][1], 0, 0, 0);
        acc[0][2] = __builtin_amdgcn_mfma_f32_16x16x32_bf16(a0c, bbuf[s & 1][2], acc[0][2], 0, 0, 0);
        acc[0][3] = __builtin_amdgcn_mfma_f32_16x16x32_bf16(a0c, bbuf[s & 1][3], acc[0][3], 0, 0, 0);
        acc[1][0] = __builtin_amdgcn_mfma_f32_16x16x32_bf16(a1c, bbuf[s & 1][0], acc[1][0], 0, 0, 0);
        acc[1][1] = __builtin_amdgcn_mfma_f32_16x16x32_bf16(a1c, bbuf[s & 1][1], acc[1][1], 0, 0, 0);
        acc[1][2] = __builtin_amdgcn_mfma_f32_16x16x32_bf16(a1c, bbuf[s & 1][2], acc[1][2], 0, 0, 0);
        acc[1][3] = __builtin_amdgcn_mfma_f32_16x16x32_bf16(a1c, bbuf[s & 1][3], acc[1][3], 0, 0, 0);
        // B prefetch for step s+2 into the slot just consumed (wraps, L1-hot)
        const int sn = ((s + 2) & 15) * 32;
        bbuf[s & 1][0] = *(const short8*)(bp0 + sn);
        bbuf[s & 1][1] = *(const short8*)(bp1 + sn);
        bbuf[s & 1][2] = *(const short8*)(bp2 + sn);
        bbuf[s & 1][3] = *(const short8*)(bp3 + sn);
        a0c = a0n; a1c = a1n;
    }

    // conv as one extra K=32 MFMA step: A[t][k] = sw[t + k], B = CWT
    {
        S8 ca0, ca1;
        #pragma unroll
        for (int j = 0; j < 4; ++j) {
            const int base0 = lm + lq * 8 + 2 * j;
            ca0.u[j] = cvt_pk(sw[base0],      sw[base0 + 1]);
            ca1.u[j] = cvt_pk(sw[base0 + 16], sw[base0 + 17]);
        }
        const ushort_t* cp = CWT + (size_t)ncol0 * 32 + lq * 8;
        const short8 cb0 = *(const short8*)(cp);
        const short8 cb1 = *(const short8*)(cp + 16 * 32);
        const short8 cb2 = *(const short8*)(cp + 32 * 32);
        const short8 cb3 = *(const short8*)(cp + 48 * 32);
        acc[0][0] = __builtin_amdgcn_mfma_f32_16x16x32_bf16(ca0.v, cb0, acc[0][0], 0, 0, 0);
        acc[0][1] = __builtin_amdgcn_mfma_f32_16x16x32_bf16(ca0.v, cb1, acc[0][1], 0, 0, 0);
        acc[0][2] = __builtin_amdgcn_mfma_f32_16x16x32_bf16(ca0.v, cb2, acc[0][2], 0, 0, 0);
        acc[0][3] = __builtin_amdgcn_mfma_f32_16x16x32_bf16(ca0.v, cb3, acc[0][3], 0, 0, 0);
        acc[1][0] = __builtin_amdgcn_mfma_f32_16x16x32_bf16(ca1.v, cb0, acc[1][0], 0, 0, 0);
        acc[1][1] = __builtin_amdgcn_mfma_f32_16x16x32_bf16(ca1.v, cb1, acc[1][1], 0, 0, 0);
        acc[1][2] = __builtin_amdgcn_mfma_f32_16x16x32_bf16(ca1.v, cb2, acc[1][2], 0, 0, 0);
        acc[1][3] = __builtin_amdgcn_mfma_f32_16x16x32_bf16(ca1.v, cb3, acc[1][3], 0, 0, 0);
    }

    // epilogue: zconst + tanh + v_a dot; reduce over the 16 n-lanes
    float zc[4], va[4];
    #pragma unroll
    for (int nbi = 0; nbi < 4; ++nbi) {
        const int col = ncol0 + nbi * 16;
        zc[nbi] = zconst[b * Un + col];
        va[nbi] = v_a[col];
    }
    #pragma unroll
    for (int mb = 0; mb < 2; ++mb) {
        #pragma unroll
        for (int r = 0; r < 4; ++r) {
            float ep = 0.f;
            #pragma unroll
            for (int nbi = 0; nbi < 4; ++nbi)
                ep += tanh_fast(acc[mb][nbi][r] + zc[nbi]) * va[nbi];
            ep += __shfl_xor(ep, 1, 64);
            ep += __shfl_xor(ep, 2, 64);
            ep += __shfl_xor(ep, 4, 64);
            ep += __shfl_xor(ep, 8, 64);
            if (lm == 0) ep_s[w][mb * 16 + lq * 4 + r] = ep;   // C/D: row = quad*4+reg
        }
    }
    __syncthreads();

    if (tid < 64) {
        float s = 0.f, st = 0.f;
        if (tid < TTILE) {
            const float energy = ep_s[0][tid] + ep_s[1][tid] + ep_s[2][tid] + ep_s[3][tid];
            s = __builtin_amdgcn_rcpf(1.0f + __expf(-energy));
            s_s[tid] = s;
            st = sw[15 + tid];
        }
        float ssum = s, stsum = st;
        #pragma unroll
        for (int off = 32; off >= 1; off >>= 1) {
            ssum  += __shfl_xor(ssum,  off, 64);
            stsum += __shfl_xor(stsum, off, 64);
        }
        if (tid == 0) {
            atomicAdd(&zSsum[b], ssum);
            atomicAdd(&zStsum[b], stsum);
        }
    }
    __syncthreads();

    // A/S weighted accumulation from the LDS bf16 tile; thread owns e = 2*tid, 2*tid+1
    const int e0 = tid << 1;
    float aA0 = 0.f, aA1 = 0.f, aS0 = 0.f, aS1 = 0.f;
    #pragma unroll 2
    for (int r4 = 0; r4 < TTILE / 4; ++r4) {
        const float4 sv4 = *(const float4*)&s_s[r4 * 4];
        const float4 st4 = *(const float4*)&sw[15 + r4 * 4];
        const float sv[4] = {sv4.x, sv4.y, sv4.z, sv4.w};
        const float st[4] = {st4.x, st4.y, st4.z, st4.w};
        #pragma unroll
        for (int j = 0; j < 4; ++j) {
            const int r = r4 * 4 + j;
            const uint_t mm = *(const uint_t*)&mem_s[r * LDK + e0];
            const float m0 = b2f(mm & 0xffffu);
            const float m1 = b2f(mm >> 16);
            aA0 += st[j] * m0; aA1 += st[j] * m1;
            aS0 += sv[j] * m0; aS1 += sv[j] * m1;
        }
    }
    atomicAdd(&zA[b * ENCn + e0],     aA0);
    atomicAdd(&zA[b * ENCn + e0 + 1], aA1);
    atomicAdd(&zS[b * ENCn + e0],     aS0);
    atomicAdd(&zS[b * ENCn + e0 + 1], aS1);
}

// ---------------- finalize ----------------
__global__ void k_final(const float* __restrict__ zA, const float* __restrict__ zS,
                        const float* __restrict__ zSsum, const float* __restrict__ zStsum,
                        const float* __restrict__ Wm, const float* __restrict__ bm,
                        float* __restrict__ out)
{
    const int b = blockIdx.x, e0 = blockIdx.y * 128, u = threadIdx.x;
    const float inv = 1.0f / zSsum[b];
    float a0 = 0.f, a1 = 0.f;
    #pragma unroll 4
    for (int e = e0; e < e0 + 128; e += 2) {
        const float c0 = zA[b * ENCn + e]     + zS[b * ENCn + e]     * inv;
        const float c1 = zA[b * ENCn + e + 1] + zS[b * ENCn + e + 1] * inv;
        a0 += c0 * Wm[(size_t)e * Un + u];
        a1 += c1 * Wm[(size_t)(e + 1) * Un + u];
    }
    float acc = a0 + a1;
    if (blockIdx.y == 0) acc += bm[u] * (zStsum[b] + 1.0f);
    atomicAdd(&out[b * Un + u], acc);
}

// ---------------- launch ----------------
extern "C" void kernel_launch(void* const* d_in, const int* in_sizes, int n_in,
                              void* d_out, int out_size, void* d_ws, size_t ws_size,
                              hipStream_t stream)
{
    const float* query  = (const float*)d_in[0];
    const float* state  = (const float*)d_in[1];
    const float* memory = (const float*)d_in[2];
    const float* Wq     = (const float*)d_in[3];
    const float* bq     = (const float*)d_in[4];
    const float* Wm     = (const float*)d_in[5];
    const float* bm     = (const float*)d_in[6];
    const float* Wl     = (const float*)d_in[7];
    const float* bl     = (const float*)d_in[8];
    const float* conv_w = (const float*)d_in[9];
    const float* conv_b = (const float*)d_in[10];
    const float* We     = (const float*)d_in[11];
    const float* be     = (const float*)d_in[12];
    const float* v_a    = (const float*)d_in[13];
    float* out = (float*)d_out;

    // workspace layout (float offsets)
    float* ws      = (float*)d_ws;
    float* zA      = ws;                   // 32768
    float* zS      = ws + 32768;           // 32768
    float* zSsum   = ws + 65536;           // 64
    float* zStsum  = ws + 65600;           // 64
    float* g_      = ws + 65664;           // 16384 (atomic-accumulated)
    float* zconst  = ws + 82048;           // 16384 (atomic-accumulated) -> zero ends 98432
    float* cvec    = ws + 98432;           // 256
    ushort_t* WmWeT = (ushort_t*)(ws + 98688);   // 131072 ushorts (65536 f)
    ushort_t* CWT   = (ushort_t*)(ws + 164224);  // 8192 ushorts (4096 f) -> ends 168320 f (~673 KB)

    hipMemsetAsync(ws, 0, 98432 * sizeof(float), stream);
    hipMemsetAsync(out, 0, (size_t)Bq * Un * sizeof(float), stream);

    hipLaunchKernelGGL(k_prep1, dim3(517), dim3(Un), 0, stream,
                       We, Wm, Wl, conv_w, bq, bm, bl, conv_b, WmWeT, CWT, cvec);
    hipLaunchKernelGGL(k_g, dim3(Bq, 8), dim3(Un), 0, stream, query, Wq, cvec, g_);
    hipLaunchKernelGGL(k_zconst, dim3(Bq, 4), dim3(Un), 0, stream, g_, We, be, zconst);
    hipLaunchKernelGGL(attn_main, dim3(Bq * NCHUNK), dim3(256), 0, stream,
                       memory, state, WmWeT, CWT, zconst, v_a, zA, zS, zSsum, zStsum);
    hipLaunchKernelGGL(k_final, dim3(Bq, 4), dim3(Un), 0, stream,
                       zA, zS, zSsum, zStsum, Wm, bm, out);
}